// Round 14
// baseline (160.002 us; speedup 1.0000x reference)
//
#include <hip/hip_runtime.h>
#include <hip/hip_cooperative_groups.h>
#include <cmath>

namespace cg = cooperative_groups;

namespace {

constexpr int B_ = 128;
constexpr int N_ = 64;
constexpr int T_ = 512;
constexpr int K_ = 5;
constexpr int NBINS = 257;   // T/2 + 1
constexpr int PMAX = 2184;   // T*T // 120
constexpr int FROWS = 8;     // rows per block (2 rows = 1 packed FFT per wave)
constexpr int CHUNKS = N_ / FROWS;  // 8 mag-partial chunks per batch
constexpr int GRID = B_ * N_ / FROWS;  // 1024 = 4 blocks/CU x 256 CUs (co-resident)

struct cpx { float re, im; };
__device__ __forceinline__ cpx cadd(cpx a, cpx b) { return {a.re + b.re, a.im + b.im}; }
__device__ __forceinline__ cpx csub(cpx a, cpx b) { return {a.re - b.re, a.im - b.im}; }
__device__ __forceinline__ cpx cmul(cpx a, cpx b) {
  return {a.re * b.re - a.im * b.im, a.re * b.im + a.im * b.re};
}

// Full complex radix-8 DFT on named scalars. t_c = sum_w z_w * W8^{w*c}.
__device__ __forceinline__ void radix8(
    cpx z0, cpx z1, cpx z2, cpx z3, cpx z4, cpx z5, cpx z6, cpx z7,
    cpx& t0, cpx& t1, cpx& t2, cpx& t3, cpx& t4, cpx& t5, cpx& t6, cpx& t7) {
  const float c = 0.70710678118654752f;
  cpx a0 = cadd(z0, z4), a1 = csub(z0, z4);
  cpx a2 = cadd(z2, z6), a3 = csub(z2, z6);
  cpx a4 = cadd(z1, z5), a5 = csub(z1, z5);
  cpx a6 = cadd(z3, z7), a7 = csub(z3, z7);
  cpx b0 = cadd(a0, a2), b1 = csub(a0, a2);
  cpx b2 = cadd(a4, a6), b3 = csub(a4, a6);
  t0 = cadd(b0, b2);
  t4 = csub(b0, b2);
  t2 = {b1.re + b3.im, b1.im - b3.re};   // b1 - i*b3
  t6 = {b1.re - b3.im, b1.im + b3.re};   // b1 + i*b3
  cpx ua5  = {c * (a5.re + a5.im), c * (a5.im - a5.re)};  // u*a5,  u = c(1-i)
  cpx usa5 = {c * (a5.re - a5.im), c * (a5.re + a5.im)};  // u"*a5, u" = c(1+i)
  cpx ua7  = {c * (a7.re + a7.im), c * (a7.im - a7.re)};
  cpx usa7 = {c * (a7.re - a7.im), c * (a7.re + a7.im)};
  cpx mia3 = {a3.im, -a3.re};
  cpx pia3 = {-a3.im, a3.re};
  t1 = cadd(cadd(a1, ua5), csub(mia3, usa7));
  t3 = cadd(csub(a1, usa5), cadd(pia3, ua7));
  t5 = cadd(csub(a1, ua5), cadd(mia3, usa7));
  t7 = cadd(cadd(a1, usa5), csub(pia3, ua7));
}

__device__ __forceinline__ void lds_fence() {
  // Cross-lane LDS read->write hazards are invisible to per-lane alias
  // analysis; pin instruction order at phase boundaries (compile-time only).
  __builtin_amdgcn_sched_barrier(0);
}

// f32 prefix scan of one 512-row into P[0..512] (R13 trend scan, verbatim).
__device__ __forceinline__ void scan_row(const float* __restrict__ src, int lane,
                                         float* __restrict__ P) {
  const float4 v0 = *reinterpret_cast<const float4*>(src + (lane << 3));
  const float4 v1 = *reinterpret_cast<const float4*>(src + (lane << 3) + 4);
  const float e0 = v0.x;
  const float e1 = e0 + v0.y;
  const float e2 = e1 + v0.z;
  const float e3 = e2 + v0.w;
  const float e4 = e3 + v1.x;
  const float e5 = e4 + v1.y;
  const float e6 = e5 + v1.z;
  const float e7 = e6 + v1.w;  // inclusive prefix within the 8-chunk
  float v = e7;
#pragma unroll
  for (int off = 1; off < 64; off <<= 1) {
    const float o = __shfl_up(v, off);
    if (lane >= off) v += o;
  }
  const float base = v - e7;  // exclusive prefix of this lane's chunk
  if (lane == 0) P[0] = 0.0f;
  const int p0 = (lane << 3) + 1;
  P[p0 + 0] = base + e0;
  P[p0 + 1] = base + e1;
  P[p0 + 2] = base + e2;
  P[p0 + 3] = base + e3;
  P[p0 + 4] = base + e4;
  P[p0 + 5] = base + e5;
  P[p0 + 6] = base + e6;
  P[p0 + 7] = base + e7;
}

// ---------------- Fused cooperative kernel ------------------------------------
// grid = 1024 blocks x 256 threads, co-resident (4 blocks/CU).
// Phase A: packed radix-8^3 FFT mags for the block's 8 rows -> magp (R13 code).
// Pre-sync: each wave scans 2 of the block's rows into its own dead LDS planes
//   (x rows are L2-hot from phase A: 2 MB/XCD < 4 MB L2).
// grid.sync() publishes magp across XCDs (the R5-safe handoff).
// Phase B: m staging + wave0 top-5 + windowed means (R13 trend code).
__global__ __launch_bounds__(256, 4) void fused_fft_trend_kernel(
    const float* __restrict__ x, float* __restrict__ magp,
    float* __restrict__ out) {
  const int tid = threadIdx.x;
  const int w = tid >> 6;
  const int lane = tid & 63;
  const int rowA = blockIdx.x * FROWS + 2 * w;  // fft rows 2w, 2w+1
  const int b = blockIdx.x >> 3;                // 8 blocks per batch

  __shared__ float bre[4][576];   // per-wave planes, stride-9 rows (18.4 KB)
  __shared__ float bim[4][576];
  __shared__ float m[NBINS];
  __shared__ int sc[K_];

  float* br = &bre[w][0];
  float* bi = &bim[w][0];

  const float* srcA = x + ((size_t)rowA << 9);
  const float* srcB = srcA + T_;

  // ======== phase A1: complex radix-8 over v (stride 64) + W512^{j*r} ========
  {
    const int j = lane;
    const cpx z0 = {srcA[j],       srcB[j]};
    const cpx z1 = {srcA[j +  64], srcB[j +  64]};
    const cpx z2 = {srcA[j + 128], srcB[j + 128]};
    const cpx z3 = {srcA[j + 192], srcB[j + 192]};
    const cpx z4 = {srcA[j + 256], srcB[j + 256]};
    const cpx z5 = {srcA[j + 320], srcB[j + 320]};
    const cpx z6 = {srcA[j + 384], srcB[j + 384]};
    const cpx z7 = {srcA[j + 448], srcB[j + 448]};
    cpx y0, y1, y2, y3, y4, y5, y6, y7;
    radix8(z0, z1, z2, z3, z4, z5, z6, z7, y0, y1, y2, y3, y4, y5, y6, y7);
    float sj, cj;
    __sincosf((float)j * 0.01227184630308513f /*2pi/512*/, &sj, &cj);
    const cpx wj = {cj, -sj};
    const int p = j * 9;
    cpx tw = wj, z;
    br[p + 0] = y0.re;            bi[p + 0] = y0.im;
    z = cmul(y1, tw); br[p + 1] = z.re; bi[p + 1] = z.im; tw = cmul(tw, wj);
    z = cmul(y2, tw); br[p + 2] = z.re; bi[p + 2] = z.im; tw = cmul(tw, wj);
    z = cmul(y3, tw); br[p + 3] = z.re; bi[p + 3] = z.im; tw = cmul(tw, wj);
    z = cmul(y4, tw); br[p + 4] = z.re; bi[p + 4] = z.im; tw = cmul(tw, wj);
    z = cmul(y5, tw); br[p + 5] = z.re; bi[p + 5] = z.im; tw = cmul(tw, wj);
    z = cmul(y6, tw); br[p + 6] = z.re; bi[p + 6] = z.im; tw = cmul(tw, wj);
    z = cmul(y7, tw); br[p + 7] = z.re; bi[p + 7] = z.im;
  }
  lds_fence();

  // ======== phase A2: complex radix-8 over w (stride 8) + W64^{i*c} ==========
  const int r2 = lane >> 3, i2 = lane & 7;
  {
    const int p = i2 * 9 + r2;
    const cpx zz0 = {br[p +   0], bi[p +   0]};
    const cpx zz1 = {br[p +  72], bi[p +  72]};
    const cpx zz2 = {br[p + 144], bi[p + 144]};
    const cpx zz3 = {br[p + 216], bi[p + 216]};
    const cpx zz4 = {br[p + 288], bi[p + 288]};
    const cpx zz5 = {br[p + 360], bi[p + 360]};
    const cpx zz6 = {br[p + 432], bi[p + 432]};
    const cpx zz7 = {br[p + 504], bi[p + 504]};
    cpx t0, t1, t2, t3, t4, t5, t6, t7;
    radix8(zz0, zz1, zz2, zz3, zz4, zz5, zz6, zz7, t0, t1, t2, t3, t4, t5, t6, t7);
    float si, ci;
    __sincosf((float)i2 * 0.09817477042468103f /*2pi/64*/, &si, &ci);
    const cpx wi = {ci, -si};
    cpx tw = wi;
    cpx y1 = cmul(t1, tw); tw = cmul(tw, wi);
    cpx y2 = cmul(t2, tw); tw = cmul(tw, wi);
    cpx y3 = cmul(t3, tw); tw = cmul(tw, wi);
    cpx y4 = cmul(t4, tw); tw = cmul(tw, wi);
    cpx y5 = cmul(t5, tw); tw = cmul(tw, wi);
    cpx y6 = cmul(t6, tw); tw = cmul(tw, wi);
    cpx y7 = cmul(t7, tw);
    lds_fence();  // all phase-2 reads before transposed writes
    const int q = r2 * 72 + i2;
    br[q +  0] = t0.re; bi[q +  0] = t0.im;
    br[q +  9] = y1.re; bi[q +  9] = y1.im;
    br[q + 18] = y2.re; bi[q + 18] = y2.im;
    br[q + 27] = y3.re; bi[q + 27] = y3.im;
    br[q + 36] = y4.re; bi[q + 36] = y4.im;
    br[q + 45] = y5.re; bi[q + 45] = y5.im;
    br[q + 54] = y6.re; bi[q + 54] = y6.im;
    br[q + 63] = y7.re; bi[q + 63] = y7.im;
  }
  lds_fence();

  // ======== phase A3: final radix-8 + in-register conjugate unpack ===========
  {
    const int r3 = lane >> 3, c3 = lane & 7;
    const int p = r3 * 72 + c3 * 9;
    const cpx yy0 = {br[p + 0], bi[p + 0]};
    const cpx yy1 = {br[p + 1], bi[p + 1]};
    const cpx yy2 = {br[p + 2], bi[p + 2]};
    const cpx yy3 = {br[p + 3], bi[p + 3]};
    const cpx yy4 = {br[p + 4], bi[p + 4]};
    const cpx yy5 = {br[p + 5], bi[p + 5]};
    const cpx yy6 = {br[p + 6], bi[p + 6]};
    const cpx yy7 = {br[p + 7], bi[p + 7]};
    cpx X0, X1, X2, X3, X4, X5, X6, X7;
    radix8(yy0, yy1, yy2, yy3, yy4, yy5, yy6, yy7, X0, X1, X2, X3, X4, X5, X6, X7);

    // mirror(k=64s+8c+r) lives at partner lane with s'=7-s (lane0: local)
    const int partner = lane == 0 ? 0 : (lane < 8 ? 8 - lane : 71 - lane);
    float m0r = __shfl(X7.re, partner), m0i = __shfl(X7.im, partner);  // s=0
    float m1r = __shfl(X6.re, partner), m1i = __shfl(X6.im, partner);  // s=1
    float m2r = __shfl(X5.re, partner), m2i = __shfl(X5.im, partner);  // s=2
    float m3r = __shfl(X4.re, partner), m3i = __shfl(X4.im, partner);  // s=3
    if (lane == 0) {
      m0r = X0.re; m0i = X0.im;
      m1r = X7.re; m1i = X7.im;
      m2r = X6.re; m2i = X6.im;
      m3r = X5.re; m3i = X5.im;
    }
    float g0, g1, g2, g3;
    {
      const float sa = X0.re + m0r, dv = X0.im - m0i, sv = X0.im + m0i, du = X0.re - m0r;
      g0 = 0.5f * (sqrtf(sa * sa + dv * dv) + sqrtf(sv * sv + du * du));
    }
    {
      const float sa = X1.re + m1r, dv = X1.im - m1i, sv = X1.im + m1i, du = X1.re - m1r;
      g1 = 0.5f * (sqrtf(sa * sa + dv * dv) + sqrtf(sv * sv + du * du));
    }
    {
      const float sa = X2.re + m2r, dv = X2.im - m2i, sv = X2.im + m2i, du = X2.re - m2r;
      g2 = 0.5f * (sqrtf(sa * sa + dv * dv) + sqrtf(sv * sv + du * du));
    }
    {
      const float sa = X3.re + m3r, dv = X3.im - m3i, sv = X3.im + m3i, du = X3.re - m3r;
      g3 = 0.5f * (sqrtf(sa * sa + dv * dv) + sqrtf(sv * sv + du * du));
    }
    lds_fence();  // own-wave phase-3 reads before mag overwrites
    const int kb = ((lane & 7) << 3) | (lane >> 3);  // 8c3 + r3
    br[kb +   0] = g0;
    br[kb +  64] = g1;
    br[kb + 128] = g2;
    br[kb + 192] = g3;
    if (lane == 0) br[256] = fabsf(X4.re) + fabsf(X4.im);  // k=256 self-mirror
  }
  __syncthreads();  // cross-wave: mags ready for the block sum

  for (int bin = tid; bin < NBINS; bin += 256) {
    magp[(size_t)blockIdx.x * NBINS + bin] =
        bre[0][bin] + bre[1][bin] + bre[2][bin] + bre[3][bin];
  }
  __syncthreads();  // all bre reads done before P overwrites

  // ======== pre-sync scans: wave w scans block rows w and w+4 ================
  // x rows are L2-hot from phase A (2 MB/XCD). P goes into the wave's own
  // dead planes: row0 -> bre[w][0..512], row1 -> bim[w][0..512].
  const int r0 = blockIdx.x * FROWS + w;
  const int r1 = r0 + 4;
  lds_fence();
  scan_row(x + ((size_t)r0 << 9), lane, br);
  scan_row(x + ((size_t)r1 << 9), lane, bi);

  __threadfence();          // release magp (belt-and-braces; sync also fences)
  cg::this_grid().sync();   // device-wide publication of magp (R5-safe)

  // ======== phase B: m staging + wave0 top-5 (R13 trend code) ================
  for (int i = tid; i < NBINS; i += 256) {
    float s = -1.0f;
    if (i != 0) {
      s = 0.0f;
      const float* mp = magp + (size_t)b * CHUNKS * NBINS + i;
#pragma unroll
      for (int c = 0; c < CHUNKS; ++c) s += mp[c * NBINS];
    }
    m[i] = s;
  }
  __syncthreads();

  if (w == 0) {
    float q0 = m[lane], q1 = m[lane + 64], q2 = m[lane + 128], q3 = m[lane + 192];
    float q4 = (lane == 0) ? m[256] : -1.0e30f;
    const int i0 = lane, i1 = lane + 64, i2x = lane + 128, i3 = lane + 192;
    const int i4 = (lane == 0) ? 256 : NBINS + 1;
#pragma unroll
    for (int kk = 0; kk < K_; ++kk) {
      float bv = q0; int bidx = i0;
      if (q1 > bv) { bv = q1; bidx = i1; }
      if (q2 > bv) { bv = q2; bidx = i2x; }
      if (q3 > bv) { bv = q3; bidx = i3; }
      if (q4 > bv) { bv = q4; bidx = i4; }
      for (int off = 32; off > 0; off >>= 1) {
        const float ov = __shfl_down(bv, off);
        const int oi = __shfl_down(bidx, off);
        if (ov > bv || (ov == bv && oi < bidx)) { bv = ov; bidx = oi; }
      }
      bidx = __shfl(bidx, 0);
      if (lane == 0) {
        // scale = floor(512 / (i * 15/64)) = 32768 / (15*i), exact integer
        int s = 32768 / (15 * bidx);
        s = s < 1 ? 1 : (s > PMAX ? PMAX : s);
        sc[kk] = s;
      }
      if (bidx == i0) q0 = -1.0e30f;
      else if (bidx == i1) q1 = -1.0e30f;
      else if (bidx == i2x) q2 = -1.0e30f;
      else if (bidx == i3) q3 = -1.0e30f;
      else if (bidx == i4) q4 = -1.0e30f;
    }
  }
  __syncthreads();  // publishes sc[]

  // ======== windows for rows r0 (P in br) and r1 (P in bi) ==================
  const float x0A = br[1], xlA = br[T_] - br[T_ - 1];
  const float x0B = bi[1], xlB = bi[T_] - bi[T_ - 1];
  float* out0 = out + (((size_t)r0 * K_) << 9);
  float* out1 = out + (((size_t)r1 * K_) << 9);
#pragma unroll
  for (int kk = 0; kk < K_; ++kk) {
    const int k = sc[kk];
    const int p = (k - 1) >> 1;
    const int Lm1 = T_ + 2 * p - k;  // L - 1
    const float invk = 1.0f / (float)k;
#pragma unroll
    for (int u = 0; u < 8; ++u) {
      const int t = lane + (u << 6);
      const int tc = t < Lm1 ? t : Lm1;
      const int lo = tc - p;       // window = [lo, lo+k) in original coords
      const int hi = lo + k;
      const int cl = lo < 0 ? -lo : 0;        // left edge replications of x[0]
      const int cr = hi > T_ ? hi - T_ : 0;   // right edge replications of x[511]
      const int loc = lo < 0 ? 0 : lo;
      const int hic = hi > T_ ? T_ : hi;
      const float sA = br[hic] - br[loc] + (float)cl * x0A + (float)cr * xlA;
      const float sB = bi[hic] - bi[loc] + (float)cl * x0B + (float)cr * xlB;
      out0[(kk << 9) + t] = sA * invk;
      out1[(kk << 9) + t] = sB * invk;
    }
  }
}

}  // namespace

extern "C" void kernel_launch(void* const* d_in, const int* in_sizes, int n_in,
                              void* d_out, int out_size, void* d_ws, size_t ws_size,
                              hipStream_t stream) {
  const float* x = (const float*)d_in[0];
  float* out = (float*)d_out;
  float* magp = (float*)d_ws;  // 1024*257 floats = 1.05 MB, rewritten each call

  void* args[] = {(void*)&x, (void*)&magp, (void*)&out};
  hipLaunchCooperativeKernel(reinterpret_cast<void*>(fused_fft_trend_kernel),
                             dim3(GRID), dim3(256), args, 0, stream);
}

// Round 15
// 32.789 us; speedup vs baseline: 4.8797x; 4.8797x over previous
//
#include <hip/hip_runtime.h>
#include <cmath>

namespace {

constexpr int B_ = 128;
constexpr int N_ = 64;
constexpr int T_ = 512;
constexpr int K_ = 5;
constexpr int NBINS = 257;   // T/2 + 1
constexpr int PMAX = 2184;   // T*T // 120
constexpr int ROWS = 4;      // trend: (b,n) rows per block, 1 per wave
constexpr int FROWS = 8;     // fft: rows per block (2 rows = 1 packed FFT per wave)
constexpr int CHUNKS = N_ / FROWS;  // 8 mag-partial chunks per batch

struct cpx { float re, im; };
__device__ __forceinline__ cpx cadd(cpx a, cpx b) { return {a.re + b.re, a.im + b.im}; }
__device__ __forceinline__ cpx csub(cpx a, cpx b) { return {a.re - b.re, a.im - b.im}; }
__device__ __forceinline__ cpx cmul(cpx a, cpx b) {
  return {a.re * b.re - a.im * b.im, a.re * b.im + a.im * b.re};
}

// Full complex radix-8 DFT on named scalars. t_c = sum_w z_w * W8^{w*c}.
__device__ __forceinline__ void radix8(
    cpx z0, cpx z1, cpx z2, cpx z3, cpx z4, cpx z5, cpx z6, cpx z7,
    cpx& t0, cpx& t1, cpx& t2, cpx& t3, cpx& t4, cpx& t5, cpx& t6, cpx& t7) {
  const float c = 0.70710678118654752f;
  cpx a0 = cadd(z0, z4), a1 = csub(z0, z4);
  cpx a2 = cadd(z2, z6), a3 = csub(z2, z6);
  cpx a4 = cadd(z1, z5), a5 = csub(z1, z5);
  cpx a6 = cadd(z3, z7), a7 = csub(z3, z7);
  cpx b0 = cadd(a0, a2), b1 = csub(a0, a2);
  cpx b2 = cadd(a4, a6), b3 = csub(a4, a6);
  t0 = cadd(b0, b2);
  t4 = csub(b0, b2);
  t2 = {b1.re + b3.im, b1.im - b3.re};   // b1 - i*b3
  t6 = {b1.re - b3.im, b1.im + b3.re};   // b1 + i*b3
  cpx ua5  = {c * (a5.re + a5.im), c * (a5.im - a5.re)};  // u*a5,  u = c(1-i)
  cpx usa5 = {c * (a5.re - a5.im), c * (a5.re + a5.im)};  // u"*a5, u" = c(1+i)
  cpx ua7  = {c * (a7.re + a7.im), c * (a7.im - a7.re)};
  cpx usa7 = {c * (a7.re - a7.im), c * (a7.re + a7.im)};
  cpx mia3 = {a3.im, -a3.re};
  cpx pia3 = {-a3.im, a3.re};
  t1 = cadd(cadd(a1, ua5), csub(mia3, usa7));
  t3 = cadd(csub(a1, usa5), cadd(pia3, ua7));
  t5 = cadd(csub(a1, ua5), cadd(mia3, usa7));
  t7 = cadd(cadd(a1, usa5), csub(pia3, ua7));
}

__device__ __forceinline__ void lds_fence() {
  // Cross-lane LDS read->write hazards are invisible to per-lane alias
  // analysis; pin instruction order at phase boundaries (compile-time only).
  __builtin_amdgcn_sched_barrier(0);
}

// ---------------- Kernel A: packed radix-8^3 FFT magnitudes -------------------
// grid = B_*N_/FROWS = 1024, block = 256 (4 waves; each wave packs 2 real rows
// into ONE complex FFT: z = a + i*b). Conjugate unpack is done IN REGISTERS via
// lane shuffles (mirror of k=64s+8c+r lives at lane 71-lane with s'=7-s), so
// only 2 LDS round-trips remain (after phase 1 and phase 2).
__global__ __launch_bounds__(256, 4) void fft_mag_kernel(const float* __restrict__ x,
                                                         float* __restrict__ magp) {
  const int tid = threadIdx.x;
  const int w = tid >> 6;
  const int lane = tid & 63;
  const int rowA = blockIdx.x * FROWS + 2 * w;  // b*64 + n

  __shared__ float bre[4][576];   // one plane pair per wave, stride-9 rows
  __shared__ float bim[4][576];

  float* br = &bre[w][0];
  float* bi = &bim[w][0];

  const float* srcA = x + ((size_t)rowA << 9);
  const float* srcB = srcA + T_;

  // ---- phase 1: complex radix-8 over v (stride 64) + twiddle W512^{j*r}
  {
    const int j = lane;
    const cpx z0 = {srcA[j],       srcB[j]};
    const cpx z1 = {srcA[j +  64], srcB[j +  64]};
    const cpx z2 = {srcA[j + 128], srcB[j + 128]};
    const cpx z3 = {srcA[j + 192], srcB[j + 192]};
    const cpx z4 = {srcA[j + 256], srcB[j + 256]};
    const cpx z5 = {srcA[j + 320], srcB[j + 320]};
    const cpx z6 = {srcA[j + 384], srcB[j + 384]};
    const cpx z7 = {srcA[j + 448], srcB[j + 448]};
    cpx y0, y1, y2, y3, y4, y5, y6, y7;
    radix8(z0, z1, z2, z3, z4, z5, z6, z7, y0, y1, y2, y3, y4, y5, y6, y7);
    float sj, cj;
    __sincosf((float)j * 0.01227184630308513f /*2pi/512*/, &sj, &cj);
    const cpx wj = {cj, -sj};
    const int p = j * 9;
    cpx tw = wj, z;
    br[p + 0] = y0.re;            bi[p + 0] = y0.im;
    z = cmul(y1, tw); br[p + 1] = z.re; bi[p + 1] = z.im; tw = cmul(tw, wj);
    z = cmul(y2, tw); br[p + 2] = z.re; bi[p + 2] = z.im; tw = cmul(tw, wj);
    z = cmul(y3, tw); br[p + 3] = z.re; bi[p + 3] = z.im; tw = cmul(tw, wj);
    z = cmul(y4, tw); br[p + 4] = z.re; bi[p + 4] = z.im; tw = cmul(tw, wj);
    z = cmul(y5, tw); br[p + 5] = z.re; bi[p + 5] = z.im; tw = cmul(tw, wj);
    z = cmul(y6, tw); br[p + 6] = z.re; bi[p + 6] = z.im; tw = cmul(tw, wj);
    z = cmul(y7, tw); br[p + 7] = z.re; bi[p + 7] = z.im;
  }
  lds_fence();

  // ---- phase 2: complex radix-8 over w (stride 8) + twiddle W64^{i*c}
  const int r2 = lane >> 3, i2 = lane & 7;
  {
    const int p = i2 * 9 + r2;
    const cpx zz0 = {br[p +   0], bi[p +   0]};
    const cpx zz1 = {br[p +  72], bi[p +  72]};
    const cpx zz2 = {br[p + 144], bi[p + 144]};
    const cpx zz3 = {br[p + 216], bi[p + 216]};
    const cpx zz4 = {br[p + 288], bi[p + 288]};
    const cpx zz5 = {br[p + 360], bi[p + 360]};
    const cpx zz6 = {br[p + 432], bi[p + 432]};
    const cpx zz7 = {br[p + 504], bi[p + 504]};
    cpx t0, t1, t2, t3, t4, t5, t6, t7;
    radix8(zz0, zz1, zz2, zz3, zz4, zz5, zz6, zz7, t0, t1, t2, t3, t4, t5, t6, t7);
    float si, ci;
    __sincosf((float)i2 * 0.09817477042468103f /*2pi/64*/, &si, &ci);
    const cpx wi = {ci, -si};
    cpx tw = wi;
    cpx y1 = cmul(t1, tw); tw = cmul(tw, wi);
    cpx y2 = cmul(t2, tw); tw = cmul(tw, wi);
    cpx y3 = cmul(t3, tw); tw = cmul(tw, wi);
    cpx y4 = cmul(t4, tw); tw = cmul(tw, wi);
    cpx y5 = cmul(t5, tw); tw = cmul(tw, wi);
    cpx y6 = cmul(t6, tw); tw = cmul(tw, wi);
    cpx y7 = cmul(t7, tw);
    lds_fence();  // all phase-2 reads before transposed writes
    const int q = r2 * 72 + i2;
    br[q +  0] = t0.re; bi[q +  0] = t0.im;
    br[q +  9] = y1.re; bi[q +  9] = y1.im;
    br[q + 18] = y2.re; bi[q + 18] = y2.im;
    br[q + 27] = y3.re; bi[q + 27] = y3.im;
    br[q + 36] = y4.re; bi[q + 36] = y4.im;
    br[q + 45] = y5.re; bi[q + 45] = y5.im;
    br[q + 54] = y6.re; bi[q + 54] = y6.im;
    br[q + 63] = y7.re; bi[q + 63] = y7.im;
  }
  lds_fence();

  // ---- phase 3: final radix-8 (lane holds Z[64s + 8c3 + r3], s=0..7 in regs)
  {
    const int r3 = lane >> 3, c3 = lane & 7;
    const int p = r3 * 72 + c3 * 9;
    const cpx yy0 = {br[p + 0], bi[p + 0]};
    const cpx yy1 = {br[p + 1], bi[p + 1]};
    const cpx yy2 = {br[p + 2], bi[p + 2]};
    const cpx yy3 = {br[p + 3], bi[p + 3]};
    const cpx yy4 = {br[p + 4], bi[p + 4]};
    const cpx yy5 = {br[p + 5], bi[p + 5]};
    const cpx yy6 = {br[p + 6], bi[p + 6]};
    const cpx yy7 = {br[p + 7], bi[p + 7]};
    cpx X0, X1, X2, X3, X4, X5, X6, X7;
    radix8(yy0, yy1, yy2, yy3, yy4, yy5, yy6, yy7, X0, X1, X2, X3, X4, X5, X6, X7);

    // ---- in-register conjugate unpack: mirror(k) at partner lane, s'=7-s.
    const int partner = lane == 0 ? 0 : (lane < 8 ? 8 - lane : 71 - lane);
    float m0r = __shfl(X7.re, partner), m0i = __shfl(X7.im, partner);  // s=0
    float m1r = __shfl(X6.re, partner), m1i = __shfl(X6.im, partner);  // s=1
    float m2r = __shfl(X5.re, partner), m2i = __shfl(X5.im, partner);  // s=2
    float m3r = __shfl(X4.re, partner), m3i = __shfl(X4.im, partner);  // s=3
    if (lane == 0) {  // lane 0: s' = (8-s)&7, all local
      m0r = X0.re; m0i = X0.im;
      m1r = X7.re; m1i = X7.im;
      m2r = X6.re; m2i = X6.im;
      m3r = X5.re; m3i = X5.im;
    }
    // |A[k]|+|B[k]| = 0.5*( |Z+conj(M)| + |Z-conj(M)| ) (component form)
    float g0, g1, g2, g3;
    {
      const float sa = X0.re + m0r, dv = X0.im - m0i, sv = X0.im + m0i, du = X0.re - m0r;
      g0 = 0.5f * (sqrtf(sa * sa + dv * dv) + sqrtf(sv * sv + du * du));
    }
    {
      const float sa = X1.re + m1r, dv = X1.im - m1i, sv = X1.im + m1i, du = X1.re - m1r;
      g1 = 0.5f * (sqrtf(sa * sa + dv * dv) + sqrtf(sv * sv + du * du));
    }
    {
      const float sa = X2.re + m2r, dv = X2.im - m2i, sv = X2.im + m2i, du = X2.re - m2r;
      g2 = 0.5f * (sqrtf(sa * sa + dv * dv) + sqrtf(sv * sv + du * du));
    }
    {
      const float sa = X3.re + m3r, dv = X3.im - m3i, sv = X3.im + m3i, du = X3.re - m3r;
      g3 = 0.5f * (sqrtf(sa * sa + dv * dv) + sqrtf(sv * sv + du * du));
    }
    lds_fence();  // own-wave phase-3 reads before mag overwrites
    const int kb = ((lane & 7) << 3) | (lane >> 3);  // 8c3 + r3
    br[kb +   0] = g0;
    br[kb +  64] = g1;
    br[kb + 128] = g2;
    br[kb + 192] = g3;
    if (lane == 0) br[256] = fabsf(X4.re) + fabsf(X4.im);  // k=256 self-mirror
  }
  __syncthreads();  // the only cross-wave handoff

  for (int bin = tid; bin < NBINS; bin += 256) {
    magp[(size_t)blockIdx.x * NBINS + bin] =
        bre[0][bin] + bre[1][bin] + bre[2][bin] + bre[3][bin];
  }
}

// ---------------- Kernel B: fused per-block top-k + f32 scan + windows --------
// grid = B_*N_/ROWS = 2048, block = 256 (4 waves, one (b,n) row per wave).
// Parallel m[] staging across 256 threads; wave 0's top-k overlaps waves 1-3's
// scans between the two barriers; plain stores. Separate dispatch from fft:
// the kernel boundary is the XCD-coherence-safe magp publication (R5 lesson;
// grid.sync() costs O(100 us) on MI355X -- R14 lesson).
__global__ __launch_bounds__(256) void trend_topk_kernel(const float* __restrict__ x,
                                                         const float* __restrict__ magp,
                                                         float* __restrict__ out) {
  const int tid = threadIdx.x;
  const int w = tid >> 6;
  const int lane = tid & 63;
  const int bn = blockIdx.x * ROWS + w;  // b*64 + n
  const int b = bn >> 6;                 // all 4 rows same batch

  __shared__ float m[NBINS];
  __shared__ int sc[K_];
  __shared__ float P[ROWS][T_ + 1];  // 8.2 KB

  // ---- batch magnitude sums (parallel across 256 threads)
  for (int i = tid; i < NBINS; i += 256) {
    float s = -1.0f;
    if (i != 0) {
      s = 0.0f;
      const float* mp = magp + (size_t)b * CHUNKS * NBINS + i;
#pragma unroll
      for (int c = 0; c < CHUNKS; ++c) s += mp[c * NBINS];
    }
    m[i] = s;
  }
  __syncthreads();

  // ---- wave 0: all-register top-5 (jax tie-break: lower index)
  if (w == 0) {
    float q0 = m[lane], q1 = m[lane + 64], q2 = m[lane + 128], q3 = m[lane + 192];
    float q4 = (lane == 0) ? m[256] : -1.0e30f;
    const int i0 = lane, i1 = lane + 64, i2x = lane + 128, i3 = lane + 192;
    const int i4 = (lane == 0) ? 256 : NBINS + 1;
#pragma unroll
    for (int kk = 0; kk < K_; ++kk) {
      float bv = q0; int bi = i0;
      if (q1 > bv) { bv = q1; bi = i1; }
      if (q2 > bv) { bv = q2; bi = i2x; }
      if (q3 > bv) { bv = q3; bi = i3; }
      if (q4 > bv) { bv = q4; bi = i4; }
      for (int off = 32; off > 0; off >>= 1) {
        const float ov = __shfl_down(bv, off);
        const int oi = __shfl_down(bi, off);
        if (ov > bv || (ov == bv && oi < bi)) { bv = ov; bi = oi; }
      }
      bi = __shfl(bi, 0);
      if (lane == 0) {
        // scale = floor(512 / (i * 15/64)) = 32768 / (15*i), exact integer
        int s = 32768 / (15 * bi);
        s = s < 1 ? 1 : (s > PMAX ? PMAX : s);
        sc[kk] = s;
      }
      if (bi == i0) q0 = -1.0e30f;
      else if (bi == i1) q1 = -1.0e30f;
      else if (bi == i2x) q2 = -1.0e30f;
      else if (bi == i3) q3 = -1.0e30f;
      else if (bi == i4) q4 = -1.0e30f;
    }
  }

  // ---- per-wave f32 prefix scan of own row (concurrent with wave-0 topk)
  const float* src = x + ((size_t)bn << 9);
  const float4 v0 = *reinterpret_cast<const float4*>(src + (lane << 3));
  const float4 v1 = *reinterpret_cast<const float4*>(src + (lane << 3) + 4);

  float e0 = v0.x;
  float e1 = e0 + v0.y;
  float e2 = e1 + v0.z;
  float e3 = e2 + v0.w;
  float e4 = e3 + v1.x;
  float e5 = e4 + v1.y;
  float e6 = e5 + v1.z;
  float e7 = e6 + v1.w;  // inclusive prefix within the 8-chunk

  float v = e7;
  for (int off = 1; off < 64; off <<= 1) {
    const float o = __shfl_up(v, off);
    if (lane >= off) v += o;
  }
  const float base = v - e7;  // exclusive prefix of this lane's chunk

  float* Pw = P[w];
  if (lane == 0) Pw[0] = 0.0f;
  const int p0 = (lane << 3) + 1;
  Pw[p0 + 0] = base + e0;
  Pw[p0 + 1] = base + e1;
  Pw[p0 + 2] = base + e2;
  Pw[p0 + 3] = base + e3;
  Pw[p0 + 4] = base + e4;
  Pw[p0 + 5] = base + e5;
  Pw[p0 + 6] = base + e6;
  Pw[p0 + 7] = base + e7;
  __syncthreads();  // publishes sc[] and P

  const float x0 = Pw[1];
  const float xl = Pw[T_] - Pw[T_ - 1];

  float* outbn = out + (((size_t)bn * K_) << 9);
#pragma unroll
  for (int kk = 0; kk < K_; ++kk) {
    const int k = sc[kk];
    const int p = (k - 1) >> 1;
    const int Lm1 = T_ + 2 * p - k;  // L - 1
    const float invk = 1.0f / (float)k;
#pragma unroll
    for (int u = 0; u < 8; ++u) {
      const int t = lane + (u << 6);
      const int tc = t < Lm1 ? t : Lm1;
      const int lo = tc - p;       // window = [lo, lo+k) in original coords
      const int hi = lo + k;
      const int cl = lo < 0 ? -lo : 0;        // left edge replications of x[0]
      const int cr = hi > T_ ? hi - T_ : 0;   // right edge replications of x[511]
      const int loc = lo < 0 ? 0 : lo;
      const int hic = hi > T_ ? T_ : hi;
      const float sum = Pw[hic] - Pw[loc] + (float)cl * x0 + (float)cr * xl;
      outbn[(kk << 9) + t] = sum * invk;
    }
  }
}

}  // namespace

extern "C" void kernel_launch(void* const* d_in, const int* in_sizes, int n_in,
                              void* d_out, int out_size, void* d_ws, size_t ws_size,
                              hipStream_t stream) {
  const float* x = (const float*)d_in[0];
  float* out = (float*)d_out;

  // magp (1024*257 floats = 1.05 MB) lives in d_ws; fully rewritten each call.
  float* magp = (float*)d_ws;

  hipLaunchKernelGGL(fft_mag_kernel, dim3(B_ * N_ / FROWS), dim3(256), 0, stream, x, magp);
  hipLaunchKernelGGL(trend_topk_kernel, dim3(B_ * N_ / ROWS), dim3(256), 0, stream, x, magp, out);
}